// Round 7
// baseline (1534.992 us; speedup 1.0000x reference)
//
#include <hip/hip_runtime.h>
#include <hip/hip_bf16.h>

#define NEG_SLOPE 0.2f
#define BSHIFT 8                 // 256 dsts per bucket
#define BSIZE  (1 << BSHIFT)
#define CAP    9216              // pairs capacity per bucket (mean 8192, +11 sigma)
#define NBMAX  400               // max buckets (n<=102400)
#define SRC_MASK 0x1FFFF         // 17 bits for src id (n < 131072)

__device__ __forceinline__ float lrelu(float x) { return fmaxf(x, NEG_SLOPE * x); }
__device__ __forceinline__ float bf2f(unsigned short u) {
    return __uint_as_float((unsigned)u << 16);
}
__device__ __forceinline__ unsigned short f2bf(float f) {
    unsigned u = __float_as_uint(f);
    return (unsigned short)((u + 0x7fffu + ((u >> 16) & 1u)) >> 16);  // RNE
}

// Pass 1: h = A @ W as a classic LDS-tiled register GEMM.
// 64x64 tile / block (256 thr), A staged transposed (stride 68), W row-major
// (stride 68). Thread (ty,tx) computes a 4x4 register tile; per k-step:
// 2x ds_read_b128 + 16 fma, LDS offsets all compile-time immediates.
// k-loop unroll CAPPED at 4: full unroll hoisted 128 ds_reads -> 256 VGPR
// + scratch spill (WRITE_SIZE 142MB, occupancy 9.6%, 107us in round 3).
// Fused: h16 (bf16 pack) + s_i/s_j via per-thread col-partials + shfl tree.
__global__ __launch_bounds__(256, 4) void k_gemm(
    const float* __restrict__ A, const float* __restrict__ W,
    const float* __restrict__ att,
    unsigned short* __restrict__ h16, float* __restrict__ s_i, float* __restrict__ s_j, int n)
{
    __shared__ float At[64 * 68];   // At[k*68 + r] = A[row0+r][k]
    __shared__ float Wl[64 * 68];   // Wl[k*68 + c] = W[k][c]
    const int tid  = threadIdx.x;
    const int lane = tid & 63;
    const int tx = tid & 15, ty = tid >> 4;
    const int r0 = ty * 4, c0 = tx * 4;
    const long row0 = (long)blockIdx.x * 64;

    {
        int r = tid & 63;
        int kb = (tid >> 6) * 4;
        long gr = row0 + r; if (gr >= n) gr = n - 1;
        const float4* Ar = (const float4*)(A + gr * 64);
#pragma unroll
        for (int p = 0; p < 4; ++p) {
            int k0 = p * 16 + kb;
            float4 a = Ar[k0 >> 2];
            At[(k0 + 0) * 68 + r] = a.x;
            At[(k0 + 1) * 68 + r] = a.y;
            At[(k0 + 2) * 68 + r] = a.z;
            At[(k0 + 3) * 68 + r] = a.w;
        }
        int c = (tid & 15) * 4;
        int rr = tid >> 4;
#pragma unroll
        for (int p = 0; p < 4; ++p) {
            int k = rr + p * 16;
            *(float4*)&Wl[k * 68 + c] = *(const float4*)(W + k * 64 + c);
        }
    }
    __syncthreads();

    float acc[4][4] = {};
#pragma unroll 4
    for (int k = 0; k < 64; ++k) {
        float4 a = *(const float4*)&At[k * 68 + r0];
        float4 w = *(const float4*)&Wl[k * 68 + c0];
        acc[0][0] = fmaf(a.x, w.x, acc[0][0]);
        acc[0][1] = fmaf(a.x, w.y, acc[0][1]);
        acc[0][2] = fmaf(a.x, w.z, acc[0][2]);
        acc[0][3] = fmaf(a.x, w.w, acc[0][3]);
        acc[1][0] = fmaf(a.y, w.x, acc[1][0]);
        acc[1][1] = fmaf(a.y, w.y, acc[1][1]);
        acc[1][2] = fmaf(a.y, w.z, acc[1][2]);
        acc[1][3] = fmaf(a.y, w.w, acc[1][3]);
        acc[2][0] = fmaf(a.z, w.x, acc[2][0]);
        acc[2][1] = fmaf(a.z, w.y, acc[2][1]);
        acc[2][2] = fmaf(a.z, w.z, acc[2][2]);
        acc[2][3] = fmaf(a.z, w.w, acc[2][3]);
        acc[3][0] = fmaf(a.w, w.x, acc[3][0]);
        acc[3][1] = fmaf(a.w, w.y, acc[3][1]);
        acc[3][2] = fmaf(a.w, w.z, acc[3][2]);
        acc[3][3] = fmaf(a.w, w.w, acc[3][3]);
    }

    const int rowlim = (int)(((long)n - row0) < 64 ? (n - row0) : 64);

#pragma unroll
    for (int i = 0; i < 4; ++i) {
        int r = r0 + i;
        if (r < rowlim) {
            uint2 uv;
            uv.x = (unsigned)f2bf(acc[i][0]) | ((unsigned)f2bf(acc[i][1]) << 16);
            uv.y = (unsigned)f2bf(acc[i][2]) | ((unsigned)f2bf(acc[i][3]) << 16);
            *(uint2*)(h16 + (row0 + r) * 64 + c0) = uv;
        }
    }

    float4 avi = *(const float4*)(att + c0);
    float4 avj = *(const float4*)(att + 64 + c0);
#pragma unroll
    for (int i = 0; i < 4; ++i) {
        float pi = acc[i][0] * avi.x;
        pi = fmaf(acc[i][1], avi.y, pi);
        pi = fmaf(acc[i][2], avi.z, pi);
        pi = fmaf(acc[i][3], avi.w, pi);
        float pj = acc[i][0] * avj.x;
        pj = fmaf(acc[i][1], avj.y, pj);
        pj = fmaf(acc[i][2], avj.z, pj);
        pj = fmaf(acc[i][3], avj.w, pj);
#pragma unroll
        for (int o = 1; o <= 8; o <<= 1) {
            pi += __shfl_xor(pi, o, 64);
            pj += __shfl_xor(pj, o, 64);
        }
        int r = r0 + i;
        if ((lane & 15) == 0 && r < rowlim) {
            s_i[row0 + r] = pi;
            s_j[row0 + r] = pj;
        }
    }
}

// Bin step A: count per bucket in LDS, reserve global bucket space, emit packed pairs.
__global__ __launch_bounds__(256) void k_binA(
    const int* __restrict__ edges, int* __restrict__ bcursor,
    unsigned* __restrict__ pairs, int n_edges, int nb)
{
    __shared__ int hist[NBMAX];
    __shared__ int cur[NBMAX];
    int t = threadIdx.x;
    for (int b = t; b < nb; b += 256) hist[b] = 0;
    __syncthreads();
    long base = (long)blockIdx.x * 8192;

    for (int k = 0; k < 32; ++k) {
        long e = base + k * 256 + t;
        if (e < n_edges) {
            int d = edges[e];
            int i = (int)(e >> 5);
            if (d != i) atomicAdd(&hist[d >> BSHIFT], 1);
        }
    }
    __syncthreads();

    for (int b = t; b < nb; b += 256) {
        int c = hist[b];
        int g = 0;
        if (c) g = atomicAdd(&bcursor[b], c);
        cur[b] = b * CAP + g;
    }
    __syncthreads();

    for (int k = 0; k < 32; ++k) {
        long e = base + k * 256 + t;
        if (e < n_edges) {
            int d = edges[e];
            int i = (int)(e >> 5);
            if (d != i) {
                int b = d >> BSHIFT;
                int slot = atomicAdd(&cur[b], 1);
                if (slot < (b + 1) * CAP)
                    pairs[slot] = ((unsigned)(d & (BSIZE - 1)) << 17) | (unsigned)i;
            }
        }
    }
}

// Fused aggregate + epilogue: one block (512 thr) per bucket of 256 dsts.
// The full f32 accumulator panel for a bucket lives in LDS (64 dims x 256
// dsts, stride 257). Each thread owns one unsorted pair per chunk: computes
// w, then 64 fire-and-forget ds_add_f32 into acc[dim][dloc] (banks
// (dim+dloc)%32 -> ~4-way on random dloc). No sort, no srcl, no CSR.
// After one barrier: wave-per-dst epilogue (self-loop, /den, +bias,
// L2-normalize) writes out directly. Replaces k_binB + k_gather.
__global__ __launch_bounds__(512, 4) void k_fuse(
    const int* __restrict__ bcursor, const unsigned* __restrict__ pairs,
    const unsigned short* __restrict__ h16,
    const float* __restrict__ s_i, const float* __restrict__ s_j,
    const float* __restrict__ bias, float* __restrict__ out, int n)
{
    __shared__ float acc[64 * 257];   // acc[dim*257 + dloc], 64.25 KB
    __shared__ float den[BSIZE];
    __shared__ float si_l[BSIZE];
    const int b = blockIdx.x, t = threadIdx.x;
    int cnt = bcursor[b]; if (cnt > CAP) cnt = CAP;
    const long wb = (long)b * CAP;

    if (t < BSIZE) {
        int d = (b << BSHIFT) + t;
        si_l[t] = (d < n) ? s_i[d] : 0.f;
        den[t] = 0.f;
    }
    for (int i = t; i < 64 * 257; i += 512) acc[i] = 0.f;
    __syncthreads();

    for (int base = 0; base < cnt; base += 512) {
        int idx = base + t;
        if (idx < cnt) {
            unsigned pk = pairs[wb + idx];
            int dloc = pk >> 17;
            int src  = (int)(pk & SRC_MASK);
            float w = __expf(lrelu(si_l[dloc] + s_j[src]));
            atomicAdd(&den[dloc], w);
            const uint4* hp = (const uint4*)(h16 + ((long)src << 6));
            float* ac = acc + dloc;
#pragma unroll
            for (int q = 0; q < 8; ++q) {
                uint4 hv = hp[q];
                atomicAdd(ac + (8*q+0)*257, w * __uint_as_float(hv.x << 16));
                atomicAdd(ac + (8*q+1)*257, w * __uint_as_float(hv.x & 0xffff0000u));
                atomicAdd(ac + (8*q+2)*257, w * __uint_as_float(hv.y << 16));
                atomicAdd(ac + (8*q+3)*257, w * __uint_as_float(hv.y & 0xffff0000u));
                atomicAdd(ac + (8*q+4)*257, w * __uint_as_float(hv.z << 16));
                atomicAdd(ac + (8*q+5)*257, w * __uint_as_float(hv.z & 0xffff0000u));
                atomicAdd(ac + (8*q+6)*257, w * __uint_as_float(hv.w << 16));
                atomicAdd(ac + (8*q+7)*257, w * __uint_as_float(hv.w & 0xffff0000u));
            }
        }
    }
    __syncthreads();

    // Epilogue: wave per dst (lane = dim). acc reads are 2-way banked (free);
    // h16/out accesses are fully coalesced 128B/256B per wave.
    const int wv = t >> 6, lane = t & 63;
    const float bl = bias[lane];
    for (int dl = wv; dl < BSIZE; dl += 8) {
        int d = (b << BSHIFT) + dl;
        if (d >= n) break;                       // wave-uniform
        float es = __expf(lrelu(si_l[dl] + s_j[d]));
        float hd = bf2f(h16[((long)d << 6) + lane]);
        float a  = acc[lane * 257 + dl];
        float dn = den[dl] + es + 1e-16f;
        float v = fmaf(hd, es, a) / dn + bl;
        float sq = v * v;
#pragma unroll
        for (int o = 1; o <= 32; o <<= 1) sq += __shfl_xor(sq, o, 64);
        float rn = 1.f / fmaxf(sqrtf(sq), 1e-12f);
        out[((long)d << 6) + lane] = v * rn;
    }
}

extern "C" void kernel_launch(void* const* d_in, const int* in_sizes, int n_in,
                              void* d_out, int out_size, void* d_ws, size_t ws_size,
                              hipStream_t stream)
{
    const float* A    = (const float*)d_in[0]; // all_embed (n,64) f32
    const float* W    = (const float*)d_in[1]; // (64,64) f32
    const float* att  = (const float*)d_in[2]; // (128,) f32
    const float* bias = (const float*)d_in[3]; // (64,) f32
    const int* edges  = (const int*)d_in[7];   // (n,32) int32

    int n = in_sizes[0] / 64;          // 100000
    int n_edges = in_sizes[7];         // n * 32
    int nb = (n + BSIZE - 1) >> BSHIFT; // 391 buckets

    // workspace layout
    unsigned short* h16 = (unsigned short*)d_ws;    // n*64 bf16
    float* s_i      = (float*)(h16 + (long)n * 64); // n
    float* s_j      = s_i + n;                      // n
    int* bcursor    = (int*)(s_j + n);              // 512
    unsigned* pairs = (unsigned*)(bcursor + 512);   // nb*CAP

    (void)hipMemsetAsync(bcursor, 0, 512 * sizeof(int), stream);

    int blocks_rows = (n + 63) / 64;                // 64 rows per block
    k_gemm<<<blocks_rows, 256, 0, stream>>>(A, W, att, h16, s_i, s_j, n);

    int blocks_binA = (n_edges + 8191) / 8192;
    k_binA<<<blocks_binA, 256, 0, stream>>>(edges, bcursor, pairs, n_edges, nb);

    k_fuse<<<nb, 512, 0, stream>>>(bcursor, pairs, h16, s_i, s_j, bias,
                                   (float*)d_out, n);
}

// Round 8
// 272.950 us; speedup vs baseline: 5.6237x; 5.6237x over previous
//
#include <hip/hip_runtime.h>
#include <hip/hip_bf16.h>

#define NEG_SLOPE 0.2f
#define BSHIFT 8                 // 256 dsts per bucket
#define BSIZE  (1 << BSHIFT)
#define CAP    9216              // pairs capacity per bucket (mean 8192, +11 sigma)
#define NBMAX  400               // max buckets (n<=102400)
#define SRC_MASK 0x1FFFF         // 17 bits for src id (n < 131072)

__device__ __forceinline__ float lrelu(float x) { return fmaxf(x, NEG_SLOPE * x); }
__device__ __forceinline__ float bf2f(unsigned short u) {
    return __uint_as_float((unsigned)u << 16);
}
__device__ __forceinline__ unsigned short f2bf(float f) {
    unsigned u = __float_as_uint(f);
    return (unsigned short)((u + 0x7fffu + ((u >> 16) & 1u)) >> 16);  // RNE
}

// Pass 1: h = A @ W as a classic LDS-tiled register GEMM.  (round-5 version)
__global__ __launch_bounds__(256, 4) void k_gemm(
    const float* __restrict__ A, const float* __restrict__ W,
    const float* __restrict__ att,
    unsigned short* __restrict__ h16, float* __restrict__ s_i, float* __restrict__ s_j, int n)
{
    __shared__ float At[64 * 68];   // At[k*68 + r] = A[row0+r][k]
    __shared__ float Wl[64 * 68];   // Wl[k*68 + c] = W[k][c]
    const int tid  = threadIdx.x;
    const int lane = tid & 63;
    const int tx = tid & 15, ty = tid >> 4;
    const int r0 = ty * 4, c0 = tx * 4;
    const long row0 = (long)blockIdx.x * 64;

    {
        int r = tid & 63;
        int kb = (tid >> 6) * 4;
        long gr = row0 + r; if (gr >= n) gr = n - 1;
        const float4* Ar = (const float4*)(A + gr * 64);
#pragma unroll
        for (int p = 0; p < 4; ++p) {
            int k0 = p * 16 + kb;
            float4 a = Ar[k0 >> 2];
            At[(k0 + 0) * 68 + r] = a.x;
            At[(k0 + 1) * 68 + r] = a.y;
            At[(k0 + 2) * 68 + r] = a.z;
            At[(k0 + 3) * 68 + r] = a.w;
        }
        int c = (tid & 15) * 4;
        int rr = tid >> 4;
#pragma unroll
        for (int p = 0; p < 4; ++p) {
            int k = rr + p * 16;
            *(float4*)&Wl[k * 68 + c] = *(const float4*)(W + k * 64 + c);
        }
    }
    __syncthreads();

    float acc[4][4] = {};
#pragma unroll 4
    for (int k = 0; k < 64; ++k) {
        float4 a = *(const float4*)&At[k * 68 + r0];
        float4 w = *(const float4*)&Wl[k * 68 + c0];
        acc[0][0] = fmaf(a.x, w.x, acc[0][0]);
        acc[0][1] = fmaf(a.x, w.y, acc[0][1]);
        acc[0][2] = fmaf(a.x, w.z, acc[0][2]);
        acc[0][3] = fmaf(a.x, w.w, acc[0][3]);
        acc[1][0] = fmaf(a.y, w.x, acc[1][0]);
        acc[1][1] = fmaf(a.y, w.y, acc[1][1]);
        acc[1][2] = fmaf(a.y, w.z, acc[1][2]);
        acc[1][3] = fmaf(a.y, w.w, acc[1][3]);
        acc[2][0] = fmaf(a.z, w.x, acc[2][0]);
        acc[2][1] = fmaf(a.z, w.y, acc[2][1]);
        acc[2][2] = fmaf(a.z, w.z, acc[2][2]);
        acc[2][3] = fmaf(a.z, w.w, acc[2][3]);
        acc[3][0] = fmaf(a.w, w.x, acc[3][0]);
        acc[3][1] = fmaf(a.w, w.y, acc[3][1]);
        acc[3][2] = fmaf(a.w, w.z, acc[3][2]);
        acc[3][3] = fmaf(a.w, w.w, acc[3][3]);
    }

    const int rowlim = (int)(((long)n - row0) < 64 ? (n - row0) : 64);

#pragma unroll
    for (int i = 0; i < 4; ++i) {
        int r = r0 + i;
        if (r < rowlim) {
            uint2 uv;
            uv.x = (unsigned)f2bf(acc[i][0]) | ((unsigned)f2bf(acc[i][1]) << 16);
            uv.y = (unsigned)f2bf(acc[i][2]) | ((unsigned)f2bf(acc[i][3]) << 16);
            *(uint2*)(h16 + (row0 + r) * 64 + c0) = uv;
        }
    }

    float4 avi = *(const float4*)(att + c0);
    float4 avj = *(const float4*)(att + 64 + c0);
#pragma unroll
    for (int i = 0; i < 4; ++i) {
        float pi = acc[i][0] * avi.x;
        pi = fmaf(acc[i][1], avi.y, pi);
        pi = fmaf(acc[i][2], avi.z, pi);
        pi = fmaf(acc[i][3], avi.w, pi);
        float pj = acc[i][0] * avj.x;
        pj = fmaf(acc[i][1], avj.y, pj);
        pj = fmaf(acc[i][2], avj.z, pj);
        pj = fmaf(acc[i][3], avj.w, pj);
#pragma unroll
        for (int o = 1; o <= 8; o <<= 1) {
            pi += __shfl_xor(pi, o, 64);
            pj += __shfl_xor(pj, o, 64);
        }
        int r = r0 + i;
        if ((lane & 15) == 0 && r < rowlim) {
            s_i[row0 + r] = pi;
            s_j[row0 + r] = pj;
        }
    }
}

// Bin step A: count per bucket in LDS, reserve global bucket space, emit packed pairs.
// (round-5 version)
__global__ __launch_bounds__(256) void k_binA(
    const int* __restrict__ edges, int* __restrict__ bcursor,
    unsigned* __restrict__ pairs, int n_edges, int nb)
{
    __shared__ int hist[NBMAX];
    __shared__ int cur[NBMAX];
    int t = threadIdx.x;
    for (int b = t; b < nb; b += 256) hist[b] = 0;
    __syncthreads();
    long base = (long)blockIdx.x * 8192;

    for (int k = 0; k < 32; ++k) {
        long e = base + k * 256 + t;
        if (e < n_edges) {
            int d = edges[e];
            int i = (int)(e >> 5);
            if (d != i) atomicAdd(&hist[d >> BSHIFT], 1);
        }
    }
    __syncthreads();

    for (int b = t; b < nb; b += 256) {
        int c = hist[b];
        int g = 0;
        if (c) g = atomicAdd(&bcursor[b], c);
        cur[b] = b * CAP + g;
    }
    __syncthreads();

    for (int k = 0; k < 32; ++k) {
        long e = base + k * 256 + t;
        if (e < n_edges) {
            int d = edges[e];
            int i = (int)(e >> 5);
            if (d != i) {
                int b = d >> BSHIFT;
                int slot = atomicAdd(&cur[b], 1);
                if (slot < (b + 1) * CAP)
                    pairs[slot] = ((unsigned)(d & (BSIZE - 1)) << 17) | (unsigned)i;
            }
        }
    }
}

// Bin step B: ATOMIC-FREE ballot radix sort (8 passes over dloc bits 17..24).
// Round-7 measured LDS atomics at ~3 cyc/lane-op (~200 cyc/wave-op); the old
// counting-sort paid 2 atomics/edge (~16K per block). This version uses
// __ballot + popcount ranks + a 256-wide Hillis scan of per-segment counts:
// zero atomics, ~2 ds + 12 VALU per element per pass. CSR offs/counts come
// from sorted-boundary detection. One block of 512 per bucket.
__global__ __launch_bounds__(512) void k_binB(
    const int* __restrict__ bcursor, unsigned* __restrict__ pairs,
    int* __restrict__ offs, int* __restrict__ counts, int n)
{
    __shared__ unsigned bb[2][CAP];      // 72 KB ping-pong
    __shared__ int sseg[2][256];         // per-64-segment zero-counts scan
    __shared__ int offl[257];
    const int b = blockIdx.x, t = threadIdx.x;
    const int w = t >> 6, lane = t & 63;
    int cnt = bcursor[b]; if (cnt > CAP) cnt = CAP;
    const long wb = (long)b * CAP;
    const int nch = (cnt + 511) >> 9;
    const unsigned long long below = ((unsigned long long)1 << lane) - 1ull;

    // load pairs -> bb[0]
    for (int i = t; i < cnt; i += 512) bb[0][i] = pairs[wb + i];
    __syncthreads();

    int p = 0;
    for (int pass = 0; pass < 8; ++pass) {
        const int bit = 17 + pass;
        // zero scan buffer
        if (t < 256) sseg[0][t] = 0;
        __syncthreads();
        // phase 1: per-segment zero counts (segment = 64 consecutive elems)
        for (int c = 0; c < nch; ++c) {
            int i = (c << 9) + t;
            bool valid = (i < cnt);
            unsigned v = valid ? bb[p][i] : 0u;
            unsigned long long bal1 = __ballot(valid && ((v >> bit) & 1u));
            unsigned long long balv = __ballot(valid);
            int n0 = __popcll(balv) - __popcll(bal1);
            if (lane == 0) sseg[0][(c << 3) + w] = n0;
        }
        __syncthreads();
        // phase 2: inclusive Hillis scan over 256 segment counts
        int ping = 0;
        for (int d = 1; d < 256; d <<= 1) {
            if (t < 256) {
                int vv = sseg[ping][t];
                if (t >= d) vv += sseg[ping][t - d];
                sseg[ping ^ 1][t] = vv;
            }
            __syncthreads();
            ping ^= 1;
        }
        const int N0 = sseg[ping][255];
        // phase 3: stable scatter via popcount ranks
        for (int c = 0; c < nch; ++c) {
            int i = (c << 9) + t;
            bool valid = (i < cnt);
            unsigned v = valid ? bb[p][i] : 0u;
            int b1 = (int)((v >> bit) & 1u);
            unsigned long long bal1 = __ballot(valid && b1);
            unsigned long long balv = __ballot(valid);
            int seg = (c << 3) + w;
            int n0seg = __popcll(balv) - __popcll(bal1);
            int scan0ex = sseg[ping][seg] - n0seg;     // exclusive zero-prefix
            if (valid) {
                int dest;
                if (!b1) {
                    dest = scan0ex + __popcll((balv & ~bal1) & below);
                } else {
                    int pv = seg << 6; if (pv > cnt) pv = cnt;  // valid elems before seg
                    dest = N0 + (pv - scan0ex) + __popcll(bal1 & below);
                }
                bb[p ^ 1][dest] = v;
            }
        }
        __syncthreads();
        p ^= 1;
    }

    // boundary detection -> offs/counts; strip keys -> srcl (in-place in pairs)
    if (t < 257) offl[t] = cnt;
    __syncthreads();
    for (int i = t; i < cnt; i += 512) {
        int k  = (int)(bb[p][i] >> 17);
        int kp = (i > 0) ? (int)(bb[p][i - 1] >> 17) : -1;
        for (int d = kp + 1; d <= k; ++d) offl[d] = i;
    }
    __syncthreads();
    int dg = (b << BSHIFT) + t;
    if (t < BSIZE && dg < n) {
        offs[dg]   = (int)(wb + offl[t]);
        counts[dg] = offl[t + 1] - offl[t];
    }
    for (int i = t; i < cnt; i += 512)
        ((int*)pairs)[wb + i] = (int)(bb[p][i] & SRC_MASK);
}

// Gather: wave per dst, reshaped as 8 groups x 8 lanes.  (round-5 version)
__global__ __launch_bounds__(256) void k_gather(
    const int* __restrict__ offs, const int* __restrict__ counts,
    const int* __restrict__ srcl, const unsigned short* __restrict__ h16,
    const float* __restrict__ s_i, const float* __restrict__ s_j,
    const float* __restrict__ bias, float* __restrict__ out, int n)
{
    int gw = (blockIdx.x * 256 + threadIdx.x) >> 6;
    int lane = threadIdx.x & 63;
    if (gw >= n) return;
    const int d = gw;
    const int off = offs[d], deg = counts[d];
    const float si = s_i[d];
    const float es = __expf(lrelu(si + s_j[d]));   // self-loop weight

    const int g  = lane >> 3;                      // group: which edge of 8
    const int li = lane & 7;                       // dims [li*8, li*8+8)
    const char* hb = (const char*)h16 + (li << 4); // +16B per lane-in-group

    float acc[8];
#pragma unroll
    for (int i = 0; i < 8; ++i) acc[i] = 0.f;
    float denp = 0.f;

    for (int base = 0; base < deg; base += 64) {
        int t = base + lane;
        int cnt = min(64, deg - base);
        int soff = 0; float w = 0.f;
        if (t < deg) {
            int s = srcl[off + t];
            soff = s << 7;                         // byte offset of row s
            w = __expf(lrelu(si + s_j[s]));
        }
        denp += w;
        for (int j = 0; j < cnt; j += 16) {
            int i0 = j + g, i1 = j + 8 + g;
            float w0 = __shfl(w, i0, 64);
            int   o0 = __shfl(soff, i0, 64);
            float w1 = __shfl(w, i1, 64);
            int   o1 = __shfl(soff, i1, 64);
            uint4 ha = *(const uint4*)(hb + o0);
            uint4 hc = *(const uint4*)(hb + o1);
            acc[0] = fmaf(__uint_as_float(ha.x << 16),          w0, acc[0]);
            acc[1] = fmaf(__uint_as_float(ha.x & 0xffff0000u),  w0, acc[1]);
            acc[2] = fmaf(__uint_as_float(ha.y << 16),          w0, acc[2]);
            acc[3] = fmaf(__uint_as_float(ha.y & 0xffff0000u),  w0, acc[3]);
            acc[4] = fmaf(__uint_as_float(ha.z << 16),          w0, acc[4]);
            acc[5] = fmaf(__uint_as_float(ha.z & 0xffff0000u),  w0, acc[5]);
            acc[6] = fmaf(__uint_as_float(ha.w << 16),          w0, acc[6]);
            acc[7] = fmaf(__uint_as_float(ha.w & 0xffff0000u),  w0, acc[7]);
            acc[0] = fmaf(__uint_as_float(hc.x << 16),          w1, acc[0]);
            acc[1] = fmaf(__uint_as_float(hc.x & 0xffff0000u),  w1, acc[1]);
            acc[2] = fmaf(__uint_as_float(hc.y << 16),          w1, acc[2]);
            acc[3] = fmaf(__uint_as_float(hc.y & 0xffff0000u),  w1, acc[3]);
            acc[4] = fmaf(__uint_as_float(hc.z << 16),          w1, acc[4]);
            acc[5] = fmaf(__uint_as_float(hc.z & 0xffff0000u),  w1, acc[5]);
            acc[6] = fmaf(__uint_as_float(hc.w << 16),          w1, acc[6]);
            acc[7] = fmaf(__uint_as_float(hc.w & 0xffff0000u),  w1, acc[7]);
        }
    }

#pragma unroll
    for (int o = 8; o <= 32; o <<= 1) {
#pragma unroll
        for (int i = 0; i < 8; ++i)
            acc[i] += __shfl_xor(acc[i], o, 64);
    }
#pragma unroll
    for (int o = 32; o; o >>= 1) denp += __shfl_xor(denp, o, 64);

    uint4 hd = *(const uint4*)(hb + (d << 7));
    float den = denp + es + 1e-16f;
    float rden = 1.f / den;
    const float4* pb = (const float4*)(bias + (li << 3));
    float4 b0 = pb[0], b1 = pb[1];

    float v[8];
    v[0] = fmaf(__uint_as_float(hd.x << 16),         es, acc[0]) * rden + b0.x;
    v[1] = fmaf(__uint_as_float(hd.x & 0xffff0000u), es, acc[1]) * rden + b0.y;
    v[2] = fmaf(__uint_as_float(hd.y << 16),         es, acc[2]) * rden + b0.z;
    v[3] = fmaf(__uint_as_float(hd.y & 0xffff0000u), es, acc[3]) * rden + b0.w;
    v[4] = fmaf(__uint_as_float(hd.z << 16),         es, acc[4]) * rden + b1.x;
    v[5] = fmaf(__uint_as_float(hd.z & 0xffff0000u), es, acc[5]) * rden + b1.y;
    v[6] = fmaf(__uint_as_float(hd.w << 16),         es, acc[6]) * rden + b1.z;
    v[7] = fmaf(__uint_as_float(hd.w & 0xffff0000u), es, acc[7]) * rden + b1.w;

    float sq = 0.f;
#pragma unroll
    for (int i = 0; i < 8; ++i) sq = fmaf(v[i], v[i], sq);
#pragma unroll
    for (int o = 1; o <= 4; o <<= 1) sq += __shfl_xor(sq, o, 64);
    float rn = 1.f / fmaxf(sqrtf(sq), 1e-12f);

    if (g < 2) {
        float4 ov;
        if (g == 0) ov = make_float4(v[0] * rn, v[1] * rn, v[2] * rn, v[3] * rn);
        else        ov = make_float4(v[4] * rn, v[5] * rn, v[6] * rn, v[7] * rn);
        *(float4*)(out + ((long)d << 6) + (li << 3) + (g << 2)) = ov;
    }
}

extern "C" void kernel_launch(void* const* d_in, const int* in_sizes, int n_in,
                              void* d_out, int out_size, void* d_ws, size_t ws_size,
                              hipStream_t stream)
{
    const float* A    = (const float*)d_in[0]; // all_embed (n,64) f32
    const float* W    = (const float*)d_in[1]; // (64,64) f32
    const float* att  = (const float*)d_in[2]; // (128,) f32
    const float* bias = (const float*)d_in[3]; // (64,) f32
    const int* edges  = (const int*)d_in[7];   // (n,32) int32

    int n = in_sizes[0] / 64;          // 100000
    int n_edges = in_sizes[7];         // n * 32
    int nb = (n + BSIZE - 1) >> BSHIFT; // 391 buckets

    // workspace layout
    unsigned short* h16 = (unsigned short*)d_ws;    // n*64 bf16
    float* s_i      = (float*)(h16 + (long)n * 64); // n
    float* s_j      = s_i + n;                      // n
    int* offs       = (int*)(s_j + n);              // n
    int* counts     = offs + n;                     // n
    int* bcursor    = counts + n;                   // 512
    unsigned* pairs = (unsigned*)(bcursor + 512);   // nb*CAP (aliased as srcl after binB)

    (void)hipMemsetAsync(bcursor, 0, 512 * sizeof(int), stream);

    int blocks_rows = (n + 63) / 64;                // 64 rows per block
    k_gemm<<<blocks_rows, 256, 0, stream>>>(A, W, att, h16, s_i, s_j, n);

    int blocks_binA = (n_edges + 8191) / 8192;
    k_binA<<<blocks_binA, 256, 0, stream>>>(edges, bcursor, pairs, n_edges, nb);

    k_binB<<<nb, 512, 0, stream>>>(bcursor, pairs, offs, counts, n);

    int blocks_waves = ((long)n * 64 + 255) / 256;  // wave per dst
    k_gather<<<blocks_waves, 256, 0, stream>>>(offs, counts, (const int*)pairs, h16,
                                               s_i, s_j, bias, (float*)d_out, n);
}

// Round 9
// 218.024 us; speedup vs baseline: 7.0405x; 1.2519x over previous
//
#include <hip/hip_runtime.h>
#include <hip/hip_bf16.h>

#define NEG_SLOPE 0.2f
#define BSHIFT 8                 // 256 dsts per bucket
#define BSIZE  (1 << BSHIFT)
#define CAP    9216              // pairs capacity per bucket (mean 8192, +11 sigma)
#define NBMAX  400               // max buckets (n<=102400)
#define SRC_MASK 0x1FFFF         // 17 bits for src id (n < 131072)

__device__ __forceinline__ float lrelu(float x) { return fmaxf(x, NEG_SLOPE * x); }
__device__ __forceinline__ float bf2f(unsigned short u) {
    return __uint_as_float((unsigned)u << 16);
}
__device__ __forceinline__ unsigned short f2bf(float f) {
    unsigned u = __float_as_uint(f);
    return (unsigned short)((u + 0x7fffu + ((u >> 16) & 1u)) >> 16);  // RNE
}

// Pass 1: h = A @ W as a classic LDS-tiled register GEMM.  (round-5 version)
__global__ __launch_bounds__(256, 4) void k_gemm(
    const float* __restrict__ A, const float* __restrict__ W,
    const float* __restrict__ att,
    unsigned short* __restrict__ h16, float* __restrict__ s_i, float* __restrict__ s_j, int n)
{
    __shared__ float At[64 * 68];   // At[k*68 + r] = A[row0+r][k]
    __shared__ float Wl[64 * 68];   // Wl[k*68 + c] = W[k][c]
    const int tid  = threadIdx.x;
    const int lane = tid & 63;
    const int tx = tid & 15, ty = tid >> 4;
    const int r0 = ty * 4, c0 = tx * 4;
    const long row0 = (long)blockIdx.x * 64;

    {
        int r = tid & 63;
        int kb = (tid >> 6) * 4;
        long gr = row0 + r; if (gr >= n) gr = n - 1;
        const float4* Ar = (const float4*)(A + gr * 64);
#pragma unroll
        for (int p = 0; p < 4; ++p) {
            int k0 = p * 16 + kb;
            float4 a = Ar[k0 >> 2];
            At[(k0 + 0) * 68 + r] = a.x;
            At[(k0 + 1) * 68 + r] = a.y;
            At[(k0 + 2) * 68 + r] = a.z;
            At[(k0 + 3) * 68 + r] = a.w;
        }
        int c = (tid & 15) * 4;
        int rr = tid >> 4;
#pragma unroll
        for (int p = 0; p < 4; ++p) {
            int k = rr + p * 16;
            *(float4*)&Wl[k * 68 + c] = *(const float4*)(W + k * 64 + c);
        }
    }
    __syncthreads();

    float acc[4][4] = {};
#pragma unroll 4
    for (int k = 0; k < 64; ++k) {
        float4 a = *(const float4*)&At[k * 68 + r0];
        float4 w = *(const float4*)&Wl[k * 68 + c0];
        acc[0][0] = fmaf(a.x, w.x, acc[0][0]);
        acc[0][1] = fmaf(a.x, w.y, acc[0][1]);
        acc[0][2] = fmaf(a.x, w.z, acc[0][2]);
        acc[0][3] = fmaf(a.x, w.w, acc[0][3]);
        acc[1][0] = fmaf(a.y, w.x, acc[1][0]);
        acc[1][1] = fmaf(a.y, w.y, acc[1][1]);
        acc[1][2] = fmaf(a.y, w.z, acc[1][2]);
        acc[1][3] = fmaf(a.y, w.w, acc[1][3]);
        acc[2][0] = fmaf(a.z, w.x, acc[2][0]);
        acc[2][1] = fmaf(a.z, w.y, acc[2][1]);
        acc[2][2] = fmaf(a.z, w.z, acc[2][2]);
        acc[2][3] = fmaf(a.z, w.w, acc[2][3]);
        acc[3][0] = fmaf(a.w, w.x, acc[3][0]);
        acc[3][1] = fmaf(a.w, w.y, acc[3][1]);
        acc[3][2] = fmaf(a.w, w.z, acc[3][2]);
        acc[3][3] = fmaf(a.w, w.w, acc[3][3]);
    }

    const int rowlim = (int)(((long)n - row0) < 64 ? (n - row0) : 64);

#pragma unroll
    for (int i = 0; i < 4; ++i) {
        int r = r0 + i;
        if (r < rowlim) {
            uint2 uv;
            uv.x = (unsigned)f2bf(acc[i][0]) | ((unsigned)f2bf(acc[i][1]) << 16);
            uv.y = (unsigned)f2bf(acc[i][2]) | ((unsigned)f2bf(acc[i][3]) << 16);
            *(uint2*)(h16 + (row0 + r) * 64 + c0) = uv;
        }
    }

    float4 avi = *(const float4*)(att + c0);
    float4 avj = *(const float4*)(att + 64 + c0);
#pragma unroll
    for (int i = 0; i < 4; ++i) {
        float pi = acc[i][0] * avi.x;
        pi = fmaf(acc[i][1], avi.y, pi);
        pi = fmaf(acc[i][2], avi.z, pi);
        pi = fmaf(acc[i][3], avi.w, pi);
        float pj = acc[i][0] * avj.x;
        pj = fmaf(acc[i][1], avj.y, pj);
        pj = fmaf(acc[i][2], avj.z, pj);
        pj = fmaf(acc[i][3], avj.w, pj);
#pragma unroll
        for (int o = 1; o <= 8; o <<= 1) {
            pi += __shfl_xor(pi, o, 64);
            pj += __shfl_xor(pj, o, 64);
        }
        int r = r0 + i;
        if ((lane & 15) == 0 && r < rowlim) {
            s_i[row0 + r] = pi;
            s_j[row0 + r] = pj;
        }
    }
}

// Bin step A (restructured): 512 thr / 8192 edges per block.
// Edges register-staged (ONE global read). LDS hist + Hillis scan + global
// reserve as before, but pairs are scattered into LDS first and then flushed
// per-bucket as contiguous runs -> coalesced global writes (~84B/bucket/block)
// instead of 4B random writes (~10x granule amplification before).
__global__ __launch_bounds__(512) void k_binA(
    const int* __restrict__ edges, int* __restrict__ bcursor,
    unsigned* __restrict__ pairs, int n_edges, int nb)
{
    __shared__ int hist[512];
    __shared__ int scn[512];
    __shared__ int st[512];
    __shared__ int cur[512];
    __shared__ int gbase[512];
    __shared__ unsigned lp[8192];        // 32 KB
    const int t = threadIdx.x;
    const long base = (long)blockIdx.x * 8192;

    int er[16];
#pragma unroll
    for (int k = 0; k < 16; ++k) {
        long e = base + k * 512 + t;
        int d = -1;
        if (e < n_edges) {
            d = edges[e];
            if (d == (int)(e >> 5)) d = -1;   // drop self-loop duplicates
        }
        er[k] = d;
    }

    hist[t] = 0;
    __syncthreads();
#pragma unroll
    for (int k = 0; k < 16; ++k)
        if (er[k] >= 0) atomicAdd(&hist[er[k] >> BSHIFT], 1);
    __syncthreads();

    scn[t] = hist[t];
    __syncthreads();
    for (int d = 1; d < 512; d <<= 1) {
        int v = (t >= d) ? scn[t - d] : 0;
        __syncthreads();
        scn[t] += v;
        __syncthreads();
    }
    int s0 = scn[t] - hist[t];
    st[t] = s0;
    cur[t] = s0;
    gbase[t] = 0;
    if (t < nb && hist[t] > 0) gbase[t] = atomicAdd(&bcursor[t], hist[t]);
    __syncthreads();

#pragma unroll
    for (int k = 0; k < 16; ++k) {
        int d = er[k];
        if (d >= 0) {
            int b = d >> BSHIFT;
            int slot = atomicAdd(&cur[b], 1);
            long e = base + k * 512 + t;
            lp[slot] = ((unsigned)(d & (BSIZE - 1)) << 17) | (unsigned)(e >> 5);
        }
    }
    __syncthreads();

    // coalesced flush: wave w handles buckets w, w+8, ...
    const int w = t >> 6, lane = t & 63;
    for (int b = w; b < nb; b += 8) {
        int cnt = hist[b];
        int gb  = gbase[b];
        int cw  = cnt;
        if (gb + cw > CAP) cw = CAP - gb;   // overflow guard (drop excess)
        long gdst = (long)b * CAP + gb;
        int sb = st[b];
        for (int s = lane; s < cw; s += 64)
            pairs[gdst + s] = lp[sb + s];
    }
}

// Bin step B: one block per bucket. Stage pairs in LDS, per-dst hist+scan,
// scatter into a second LDS buffer (srt), then stream out fully coalesced.
// (round-5 version: measured ~20us vs 67.8us for the ballot radix sort)
__global__ __launch_bounds__(512) void k_binB(
    const int* __restrict__ bcursor, unsigned* __restrict__ pairs,
    int* __restrict__ offs, int* __restrict__ counts, int n)
{
    __shared__ unsigned pl[CAP];         // 36 KB
    __shared__ unsigned srt[CAP];        // 36 KB
    __shared__ int hist[BSIZE];
    __shared__ int scn[BSIZE];
    __shared__ int cur[BSIZE];
    int b = blockIdx.x, t = threadIdx.x;
    int cnt = bcursor[b];
    if (cnt > CAP) cnt = CAP;
    long wb = (long)b * CAP;

    for (int s = t; s < cnt; s += 512) pl[s] = pairs[wb + s];
    if (t < BSIZE) hist[t] = 0;
    __syncthreads();
    for (int s = t; s < cnt; s += 512) atomicAdd(&hist[pl[s] >> 17], 1);
    __syncthreads();

    if (t < BSIZE) scn[t] = hist[t];
    __syncthreads();
    for (int d = 1; d < BSIZE; d <<= 1) {
        int v = (t >= d && t < BSIZE) ? scn[t - d] : 0;
        __syncthreads();
        if (t < BSIZE) scn[t] += v;
        __syncthreads();
    }
    if (t < BSIZE) {
        int start = scn[t] - hist[t];
        int dg = (b << BSHIFT) + t;
        if (dg < n) {
            offs[dg] = (int)(wb + start);
            counts[dg] = hist[t];
        }
        cur[t] = start;
    }
    __syncthreads();

    for (int s = t; s < cnt; s += 512) {
        unsigned pk = pl[s];
        int pos = atomicAdd(&cur[pk >> 17], 1);
        srt[pos] = pk & SRC_MASK;
    }
    __syncthreads();

    for (int s = t; s < cnt; s += 512)
        ((int*)pairs)[wb + s] = (int)srt[s];
}

// Gather: wave per dst, reshaped as 8 groups x 8 lanes.  (round-5 version)
__global__ __launch_bounds__(256) void k_gather(
    const int* __restrict__ offs, const int* __restrict__ counts,
    const int* __restrict__ srcl, const unsigned short* __restrict__ h16,
    const float* __restrict__ s_i, const float* __restrict__ s_j,
    const float* __restrict__ bias, float* __restrict__ out, int n)
{
    int gw = (blockIdx.x * 256 + threadIdx.x) >> 6;
    int lane = threadIdx.x & 63;
    if (gw >= n) return;
    const int d = gw;
    const int off = offs[d], deg = counts[d];
    const float si = s_i[d];
    const float es = __expf(lrelu(si + s_j[d]));   // self-loop weight

    const int g  = lane >> 3;                      // group: which edge of 8
    const int li = lane & 7;                       // dims [li*8, li*8+8)
    const char* hb = (const char*)h16 + (li << 4); // +16B per lane-in-group

    float acc[8];
#pragma unroll
    for (int i = 0; i < 8; ++i) acc[i] = 0.f;
    float denp = 0.f;

    for (int base = 0; base < deg; base += 64) {
        int t = base + lane;
        int cnt = min(64, deg - base);
        int soff = 0; float w = 0.f;
        if (t < deg) {
            int s = srcl[off + t];
            soff = s << 7;                         // byte offset of row s
            w = __expf(lrelu(si + s_j[s]));
        }
        denp += w;
        for (int j = 0; j < cnt; j += 16) {
            int i0 = j + g, i1 = j + 8 + g;
            float w0 = __shfl(w, i0, 64);
            int   o0 = __shfl(soff, i0, 64);
            float w1 = __shfl(w, i1, 64);
            int   o1 = __shfl(soff, i1, 64);
            uint4 ha = *(const uint4*)(hb + o0);
            uint4 hc = *(const uint4*)(hb + o1);
            acc[0] = fmaf(__uint_as_float(ha.x << 16),          w0, acc[0]);
            acc[1] = fmaf(__uint_as_float(ha.x & 0xffff0000u),  w0, acc[1]);
            acc[2] = fmaf(__uint_as_float(ha.y << 16),          w0, acc[2]);
            acc[3] = fmaf(__uint_as_float(ha.y & 0xffff0000u),  w0, acc[3]);
            acc[4] = fmaf(__uint_as_float(ha.z << 16),          w0, acc[4]);
            acc[5] = fmaf(__uint_as_float(ha.z & 0xffff0000u),  w0, acc[5]);
            acc[6] = fmaf(__uint_as_float(ha.w << 16),          w0, acc[6]);
            acc[7] = fmaf(__uint_as_float(ha.w & 0xffff0000u),  w0, acc[7]);
            acc[0] = fmaf(__uint_as_float(hc.x << 16),          w1, acc[0]);
            acc[1] = fmaf(__uint_as_float(hc.x & 0xffff0000u),  w1, acc[1]);
            acc[2] = fmaf(__uint_as_float(hc.y << 16),          w1, acc[2]);
            acc[3] = fmaf(__uint_as_float(hc.y & 0xffff0000u),  w1, acc[3]);
            acc[4] = fmaf(__uint_as_float(hc.z << 16),          w1, acc[4]);
            acc[5] = fmaf(__uint_as_float(hc.z & 0xffff0000u),  w1, acc[5]);
            acc[6] = fmaf(__uint_as_float(hc.w << 16),          w1, acc[6]);
            acc[7] = fmaf(__uint_as_float(hc.w & 0xffff0000u),  w1, acc[7]);
        }
    }

#pragma unroll
    for (int o = 8; o <= 32; o <<= 1) {
#pragma unroll
        for (int i = 0; i < 8; ++i)
            acc[i] += __shfl_xor(acc[i], o, 64);
    }
#pragma unroll
    for (int o = 32; o; o >>= 1) denp += __shfl_xor(denp, o, 64);

    uint4 hd = *(const uint4*)(hb + (d << 7));
    float den = denp + es + 1e-16f;
    float rden = 1.f / den;
    const float4* pb = (const float4*)(bias + (li << 3));
    float4 b0 = pb[0], b1 = pb[1];

    float v[8];
    v[0] = fmaf(__uint_as_float(hd.x << 16),         es, acc[0]) * rden + b0.x;
    v[1] = fmaf(__uint_as_float(hd.x & 0xffff0000u), es, acc[1]) * rden + b0.y;
    v[2] = fmaf(__uint_as_float(hd.y << 16),         es, acc[2]) * rden + b0.z;
    v[3] = fmaf(__uint_as_float(hd.y & 0xffff0000u), es, acc[3]) * rden + b0.w;
    v[4] = fmaf(__uint_as_float(hd.z << 16),         es, acc[4]) * rden + b1.x;
    v[5] = fmaf(__uint_as_float(hd.z & 0xffff0000u), es, acc[5]) * rden + b1.y;
    v[6] = fmaf(__uint_as_float(hd.w << 16),         es, acc[6]) * rden + b1.z;
    v[7] = fmaf(__uint_as_float(hd.w & 0xffff0000u), es, acc[7]) * rden + b1.w;

    float sq = 0.f;
#pragma unroll
    for (int i = 0; i < 8; ++i) sq = fmaf(v[i], v[i], sq);
#pragma unroll
    for (int o = 1; o <= 4; o <<= 1) sq += __shfl_xor(sq, o, 64);
    float rn = 1.f / fmaxf(sqrtf(sq), 1e-12f);

    if (g < 2) {
        float4 ov;
        if (g == 0) ov = make_float4(v[0] * rn, v[1] * rn, v[2] * rn, v[3] * rn);
        else        ov = make_float4(v[4] * rn, v[5] * rn, v[6] * rn, v[7] * rn);
        *(float4*)(out + ((long)d << 6) + (li << 3) + (g << 2)) = ov;
    }
}

extern "C" void kernel_launch(void* const* d_in, const int* in_sizes, int n_in,
                              void* d_out, int out_size, void* d_ws, size_t ws_size,
                              hipStream_t stream)
{
    const float* A    = (const float*)d_in[0]; // all_embed (n,64) f32
    const float* W    = (const float*)d_in[1]; // (64,64) f32
    const float* att  = (const float*)d_in[2]; // (128,) f32
    const float* bias = (const float*)d_in[3]; // (64,) f32
    const int* edges  = (const int*)d_in[7];   // (n,32) int32

    int n = in_sizes[0] / 64;          // 100000
    int n_edges = in_sizes[7];         // n * 32
    int nb = (n + BSIZE - 1) >> BSHIFT; // 391 buckets

    // workspace layout
    unsigned short* h16 = (unsigned short*)d_ws;    // n*64 bf16
    float* s_i      = (float*)(h16 + (long)n * 64); // n
    float* s_j      = s_i + n;                      // n
    int* offs       = (int*)(s_j + n);              // n
    int* counts     = offs + n;                     // n
    int* bcursor    = counts + n;                   // 512
    unsigned* pairs = (unsigned*)(bcursor + 512);   // nb*CAP (aliased as srcl after binB)

    (void)hipMemsetAsync(bcursor, 0, 512 * sizeof(int), stream);

    int blocks_rows = (n + 63) / 64;                // 64 rows per block
    k_gemm<<<blocks_rows, 256, 0, stream>>>(A, W, att, h16, s_i, s_j, n);

    int blocks_binA = (n_edges + 8191) / 8192;      // 391
    k_binA<<<blocks_binA, 512, 0, stream>>>(edges, bcursor, pairs, n_edges, nb);

    k_binB<<<nb, 512, 0, stream>>>(bcursor, pairs, offs, counts, n);

    int blocks_waves = ((long)n * 64 + 255) / 256;  // wave per dst
    k_gather<<<blocks_waves, 256, 0, stream>>>(offs, counts, (const int*)pairs, h16,
                                               s_i, s_j, bias, (float*)d_out, n);
}

// Round 10
// 215.633 us; speedup vs baseline: 7.1185x; 1.0111x over previous
//
#include <hip/hip_runtime.h>
#include <hip/hip_bf16.h>

#define NEG_SLOPE 0.2f
#define BSHIFT 8                 // 256 dsts per bucket
#define BSIZE  (1 << BSHIFT)
#define CAP    9216              // pairs capacity per bucket (mean 8192, +11 sigma)
#define NBMAX  400               // max buckets (n<=102400)
#define SRC_MASK 0x1FFFF         // 17 bits for src id (n < 131072)

typedef float v2f __attribute__((ext_vector_type(2)));

__device__ __forceinline__ float lrelu(float x) { return fmaxf(x, NEG_SLOPE * x); }
__device__ __forceinline__ float bf2f(unsigned short u) {
    return __uint_as_float((unsigned)u << 16);
}
__device__ __forceinline__ unsigned short f2bf(float f) {
    unsigned u = __float_as_uint(f);
    return (unsigned short)((u + 0x7fffu + ((u >> 16) & 1u)) >> 16);  // RNE
}

// Pass 1: h = A @ W as a classic LDS-tiled register GEMM.  (round-5 version)
__global__ __launch_bounds__(256, 4) void k_gemm(
    const float* __restrict__ A, const float* __restrict__ W,
    const float* __restrict__ att,
    unsigned short* __restrict__ h16, float* __restrict__ s_i, float* __restrict__ s_j, int n)
{
    __shared__ float At[64 * 68];   // At[k*68 + r] = A[row0+r][k]
    __shared__ float Wl[64 * 68];   // Wl[k*68 + c] = W[k][c]
    const int tid  = threadIdx.x;
    const int lane = tid & 63;
    const int tx = tid & 15, ty = tid >> 4;
    const int r0 = ty * 4, c0 = tx * 4;
    const long row0 = (long)blockIdx.x * 64;

    {
        int r = tid & 63;
        int kb = (tid >> 6) * 4;
        long gr = row0 + r; if (gr >= n) gr = n - 1;
        const float4* Ar = (const float4*)(A + gr * 64);
#pragma unroll
        for (int p = 0; p < 4; ++p) {
            int k0 = p * 16 + kb;
            float4 a = Ar[k0 >> 2];
            At[(k0 + 0) * 68 + r] = a.x;
            At[(k0 + 1) * 68 + r] = a.y;
            At[(k0 + 2) * 68 + r] = a.z;
            At[(k0 + 3) * 68 + r] = a.w;
        }
        int c = (tid & 15) * 4;
        int rr = tid >> 4;
#pragma unroll
        for (int p = 0; p < 4; ++p) {
            int k = rr + p * 16;
            *(float4*)&Wl[k * 68 + c] = *(const float4*)(W + k * 64 + c);
        }
    }
    __syncthreads();

    float acc[4][4] = {};
#pragma unroll 4
    for (int k = 0; k < 64; ++k) {
        float4 a = *(const float4*)&At[k * 68 + r0];
        float4 w = *(const float4*)&Wl[k * 68 + c0];
        acc[0][0] = fmaf(a.x, w.x, acc[0][0]);
        acc[0][1] = fmaf(a.x, w.y, acc[0][1]);
        acc[0][2] = fmaf(a.x, w.z, acc[0][2]);
        acc[0][3] = fmaf(a.x, w.w, acc[0][3]);
        acc[1][0] = fmaf(a.y, w.x, acc[1][0]);
        acc[1][1] = fmaf(a.y, w.y, acc[1][1]);
        acc[1][2] = fmaf(a.y, w.z, acc[1][2]);
        acc[1][3] = fmaf(a.y, w.w, acc[1][3]);
        acc[2][0] = fmaf(a.z, w.x, acc[2][0]);
        acc[2][1] = fmaf(a.z, w.y, acc[2][1]);
        acc[2][2] = fmaf(a.z, w.z, acc[2][2]);
        acc[2][3] = fmaf(a.z, w.w, acc[2][3]);
        acc[3][0] = fmaf(a.w, w.x, acc[3][0]);
        acc[3][1] = fmaf(a.w, w.y, acc[3][1]);
        acc[3][2] = fmaf(a.w, w.z, acc[3][2]);
        acc[3][3] = fmaf(a.w, w.w, acc[3][3]);
    }

    const int rowlim = (int)(((long)n - row0) < 64 ? (n - row0) : 64);

#pragma unroll
    for (int i = 0; i < 4; ++i) {
        int r = r0 + i;
        if (r < rowlim) {
            uint2 uv;
            uv.x = (unsigned)f2bf(acc[i][0]) | ((unsigned)f2bf(acc[i][1]) << 16);
            uv.y = (unsigned)f2bf(acc[i][2]) | ((unsigned)f2bf(acc[i][3]) << 16);
            *(uint2*)(h16 + (row0 + r) * 64 + c0) = uv;
        }
    }

    float4 avi = *(const float4*)(att + c0);
    float4 avj = *(const float4*)(att + 64 + c0);
#pragma unroll
    for (int i = 0; i < 4; ++i) {
        float pi = acc[i][0] * avi.x;
        pi = fmaf(acc[i][1], avi.y, pi);
        pi = fmaf(acc[i][2], avi.z, pi);
        pi = fmaf(acc[i][3], avi.w, pi);
        float pj = acc[i][0] * avj.x;
        pj = fmaf(acc[i][1], avj.y, pj);
        pj = fmaf(acc[i][2], avj.z, pj);
        pj = fmaf(acc[i][3], avj.w, pj);
#pragma unroll
        for (int o = 1; o <= 8; o <<= 1) {
            pi += __shfl_xor(pi, o, 64);
            pj += __shfl_xor(pj, o, 64);
        }
        int r = r0 + i;
        if ((lane & 15) == 0 && r < rowlim) {
            s_i[row0 + r] = pi;
            s_j[row0 + r] = pj;
        }
    }
}

// Bin step A: 512 thr / 8192 edges, register-staged, LDS-staged coalesced
// flush (round-9 structure). Scan replaced: wave-level __shfl_up inclusive
// scan + 8-entry cross-wave prefix -> 3 barriers instead of ~18.
__global__ __launch_bounds__(512) void k_binA(
    const int* __restrict__ edges, int* __restrict__ bcursor,
    unsigned* __restrict__ pairs, int n_edges, int nb)
{
    __shared__ int hist[512];
    __shared__ int st[512];
    __shared__ int cur[512];
    __shared__ int gbase[512];
    __shared__ int wsum[8];
    __shared__ unsigned lp[8192];        // 32 KB
    const int t = threadIdx.x;
    const int w = t >> 6, lane = t & 63;
    const long base = (long)blockIdx.x * 8192;

    int er[16];
#pragma unroll
    for (int k = 0; k < 16; ++k) {
        long e = base + k * 512 + t;
        int d = -1;
        if (e < n_edges) {
            d = edges[e];
            if (d == (int)(e >> 5)) d = -1;   // drop self-loops
        }
        er[k] = d;
    }

    hist[t] = 0;
    __syncthreads();
#pragma unroll
    for (int k = 0; k < 16; ++k)
        if (er[k] >= 0) atomicAdd(&hist[er[k] >> BSHIFT], 1);
    __syncthreads();

    // wave-level inclusive scan of hist (64 entries per wave)
    int hv = hist[t];
    int inc = hv;
#pragma unroll
    for (int off = 1; off < 64; off <<= 1) {
        int u = __shfl_up(inc, off, 64);
        if (lane >= off) inc += u;
    }
    if (lane == 63) wsum[w] = inc;
    __syncthreads();
    {
        int wb_ = 0;
        for (int i = 0; i < w; ++i) wb_ += wsum[i];   // wave-uniform, <=7 reads
        int s0 = inc - hv + wb_;                       // exclusive prefix
        st[t] = s0;
        cur[t] = s0;
        gbase[t] = 0;
    }
    if (t < nb && hist[t] > 0) gbase[t] = atomicAdd(&bcursor[t], hist[t]);
    __syncthreads();

#pragma unroll
    for (int k = 0; k < 16; ++k) {
        int d = er[k];
        if (d >= 0) {
            int b = d >> BSHIFT;
            int slot = atomicAdd(&cur[b], 1);
            long e = base + k * 512 + t;
            lp[slot] = ((unsigned)(d & (BSIZE - 1)) << 17) | (unsigned)(e >> 5);
        }
    }
    __syncthreads();

    // coalesced flush: wave w handles buckets w, w+8, ...
    for (int b = w; b < nb; b += 8) {
        int cnt = hist[b];
        int gb  = gbase[b];
        int cw  = cnt;
        if (gb + cw > CAP) cw = CAP - gb;   // overflow guard (drop excess)
        long gdst = (long)b * CAP + gb;
        int sb = st[b];
        for (int s = lane; s < cw; s += 64)
            pairs[gdst + s] = lp[sb + s];
    }
}

// Bin step B: counting sort per bucket (round-5 structure), scan replaced
// by wave-level __shfl_up scan + 4-entry cross-wave prefix.
__global__ __launch_bounds__(512) void k_binB(
    const int* __restrict__ bcursor, unsigned* __restrict__ pairs,
    int* __restrict__ offs, int* __restrict__ counts, int n)
{
    __shared__ unsigned pl[CAP];         // 36 KB
    __shared__ unsigned srt[CAP];        // 36 KB
    __shared__ int hist[BSIZE];
    __shared__ int cur[BSIZE];
    __shared__ int wsum[4];
    int b = blockIdx.x, t = threadIdx.x;
    const int w = t >> 6, lane = t & 63;
    int cnt = bcursor[b];
    if (cnt > CAP) cnt = CAP;
    long wb = (long)b * CAP;

    for (int s = t; s < cnt; s += 512) pl[s] = pairs[wb + s];
    if (t < BSIZE) hist[t] = 0;
    __syncthreads();
    for (int s = t; s < cnt; s += 512) atomicAdd(&hist[pl[s] >> 17], 1);
    __syncthreads();

    int hv = (t < BSIZE) ? hist[t] : 0;
    int inc = hv;
#pragma unroll
    for (int off = 1; off < 64; off <<= 1) {
        int u = __shfl_up(inc, off, 64);
        if (lane >= off) inc += u;
    }
    if (t < BSIZE && lane == 63) wsum[w] = inc;
    __syncthreads();
    if (t < BSIZE) {
        int wb_ = 0;
        for (int i = 0; i < w; ++i) wb_ += wsum[i];
        int start = inc - hv + wb_;
        int dg = (b << BSHIFT) + t;
        if (dg < n) {
            offs[dg]   = (int)(wb + start);
            counts[dg] = hv;
        }
        cur[t] = start;
    }
    __syncthreads();

    for (int s = t; s < cnt; s += 512) {
        unsigned pk = pl[s];
        int pos = atomicAdd(&cur[pk >> 17], 1);
        srt[pos] = pk & SRC_MASK;
    }
    __syncthreads();

    for (int s = t; s < cnt; s += 512)
        ((int*)pairs)[wb + s] = (int)srt[s];
}

// Gather: wave per dst, 8 groups x 8 lanes (round-5 structure).
// Accumulators paired as float2 ext-vectors -> v_pk_fma_f32 (halves fma
// issue: 16 fma -> 8 pk_fma per 16 edges). Same per-dim fma chains, so
// numerics are bit-identical to the scalar version.
__global__ __launch_bounds__(256) void k_gather(
    const int* __restrict__ offs, const int* __restrict__ counts,
    const int* __restrict__ srcl, const unsigned short* __restrict__ h16,
    const float* __restrict__ s_i, const float* __restrict__ s_j,
    const float* __restrict__ bias, float* __restrict__ out, int n)
{
    int gw = (blockIdx.x * 256 + threadIdx.x) >> 6;
    int lane = threadIdx.x & 63;
    if (gw >= n) return;
    const int d = gw;
    const int off = offs[d], deg = counts[d];
    const float si = s_i[d];
    const float es = __expf(lrelu(si + s_j[d]));   // self-loop weight

    const int g  = lane >> 3;                      // group: which edge of 8
    const int li = lane & 7;                       // dims [li*8, li*8+8)
    const char* hb = (const char*)h16 + (li << 4); // +16B per lane-in-group

    v2f acc2[4];
#pragma unroll
    for (int i = 0; i < 4; ++i) acc2[i] = (v2f)0.f;
    float denp = 0.f;

    for (int base = 0; base < deg; base += 64) {
        int t = base + lane;
        int cnt = min(64, deg - base);
        int soff = 0; float w = 0.f;
        if (t < deg) {
            int s = srcl[off + t];
            soff = s << 7;                         // byte offset of row s
            w = __expf(lrelu(si + s_j[s]));
        }
        denp += w;
        // 16 edges per iteration: 4 bpermutes + 2 dwordx4 loads + 16 pk_fma
        for (int j = 0; j < cnt; j += 16) {
            int i0 = j + g, i1 = j + 8 + g;
            float w0 = __shfl(w, i0, 64);
            int   o0 = __shfl(soff, i0, 64);
            float w1 = __shfl(w, i1, 64);
            int   o1 = __shfl(soff, i1, 64);
            uint4 ha = *(const uint4*)(hb + o0);
            uint4 hc = *(const uint4*)(hb + o1);
            v2f w0v = {w0, w0};
            v2f w1v = {w1, w1};
            v2f p;
            p = (v2f){__uint_as_float(ha.x << 16), __uint_as_float(ha.x & 0xffff0000u)};
            acc2[0] += p * w0v;
            p = (v2f){__uint_as_float(ha.y << 16), __uint_as_float(ha.y & 0xffff0000u)};
            acc2[1] += p * w0v;
            p = (v2f){__uint_as_float(ha.z << 16), __uint_as_float(ha.z & 0xffff0000u)};
            acc2[2] += p * w0v;
            p = (v2f){__uint_as_float(ha.w << 16), __uint_as_float(ha.w & 0xffff0000u)};
            acc2[3] += p * w0v;
            p = (v2f){__uint_as_float(hc.x << 16), __uint_as_float(hc.x & 0xffff0000u)};
            acc2[0] += p * w1v;
            p = (v2f){__uint_as_float(hc.y << 16), __uint_as_float(hc.y & 0xffff0000u)};
            acc2[1] += p * w1v;
            p = (v2f){__uint_as_float(hc.z << 16), __uint_as_float(hc.z & 0xffff0000u)};
            acc2[2] += p * w1v;
            p = (v2f){__uint_as_float(hc.w << 16), __uint_as_float(hc.w & 0xffff0000u)};
            acc2[3] += p * w1v;
        }
    }

    float acc[8];
    acc[0] = acc2[0].x; acc[1] = acc2[0].y;
    acc[2] = acc2[1].x; acc[3] = acc2[1].y;
    acc[4] = acc2[2].x; acc[5] = acc2[2].y;
    acc[6] = acc2[3].x; acc[7] = acc2[3].y;

    // reduce group partials: groups live in lane bits 3..5 -> xor 8,16,32
#pragma unroll
    for (int o = 8; o <= 32; o <<= 1) {
#pragma unroll
        for (int i = 0; i < 8; ++i)
            acc[i] += __shfl_xor(acc[i], o, 64);
    }
    // den partials over all 64 lanes
#pragma unroll
    for (int o = 32; o; o >>= 1) denp += __shfl_xor(denp, o, 64);

    // self loop + epilogue (all groups hold identical values from here on)
    uint4 hd = *(const uint4*)(hb + (d << 7));
    float den = denp + es + 1e-16f;
    float rden = 1.f / den;
    const float4* pb = (const float4*)(bias + (li << 3));
    float4 b0 = pb[0], b1 = pb[1];

    float v[8];
    v[0] = fmaf(__uint_as_float(hd.x << 16),         es, acc[0]) * rden + b0.x;
    v[1] = fmaf(__uint_as_float(hd.x & 0xffff0000u), es, acc[1]) * rden + b0.y;
    v[2] = fmaf(__uint_as_float(hd.y << 16),         es, acc[2]) * rden + b0.z;
    v[3] = fmaf(__uint_as_float(hd.y & 0xffff0000u), es, acc[3]) * rden + b0.w;
    v[4] = fmaf(__uint_as_float(hd.z << 16),         es, acc[4]) * rden + b1.x;
    v[5] = fmaf(__uint_as_float(hd.z & 0xffff0000u), es, acc[5]) * rden + b1.y;
    v[6] = fmaf(__uint_as_float(hd.w << 16),         es, acc[6]) * rden + b1.z;
    v[7] = fmaf(__uint_as_float(hd.w & 0xffff0000u), es, acc[7]) * rden + b1.w;

    float sq = 0.f;
#pragma unroll
    for (int i = 0; i < 8; ++i) sq = fmaf(v[i], v[i], sq);
#pragma unroll
    for (int o = 1; o <= 4; o <<= 1) sq += __shfl_xor(sq, o, 64);
    float rn = 1.f / fmaxf(sqrtf(sq), 1e-12f);

    if (g < 2) {   // groups 0/1 write dims [li*8+4g, li*8+4g+4) once each
        float4 ov;
        if (g == 0) ov = make_float4(v[0] * rn, v[1] * rn, v[2] * rn, v[3] * rn);
        else        ov = make_float4(v[4] * rn, v[5] * rn, v[6] * rn, v[7] * rn);
        *(float4*)(out + ((long)d << 6) + (li << 3) + (g << 2)) = ov;
    }
}

extern "C" void kernel_launch(void* const* d_in, const int* in_sizes, int n_in,
                              void* d_out, int out_size, void* d_ws, size_t ws_size,
                              hipStream_t stream)
{
    const float* A    = (const float*)d_in[0]; // all_embed (n,64) f32
    const float* W    = (const float*)d_in[1]; // (64,64) f32
    const float* att  = (const float*)d_in[2]; // (128,) f32
    const float* bias = (const float*)d_in[3]; // (64,) f32
    const int* edges  = (const int*)d_in[7];   // (n,32) int32

    int n = in_sizes[0] / 64;          // 100000
    int n_edges = in_sizes[7];         // n * 32
    int nb = (n + BSIZE - 1) >> BSHIFT; // 391 buckets

    // workspace layout
    unsigned short* h16 = (unsigned short*)d_ws;    // n*64 bf16
    float* s_i      = (float*)(h16 + (long)n * 64); // n
    float* s_j      = s_i + n;                      // n
    int* offs       = (int*)(s_j + n);              // n
    int* counts     = offs + n;                     // n
    int* bcursor    = counts + n;                   // 512
    unsigned* pairs = (unsigned*)(bcursor + 512);   // nb*CAP (aliased as srcl after binB)

    (void)hipMemsetAsync(bcursor, 0, 512 * sizeof(int), stream);

    int blocks_rows = (n + 63) / 64;                // 64 rows per block
    k_gemm<<<blocks_rows, 256, 0, stream>>>(A, W, att, h16, s_i, s_j, n);

    int blocks_binA = (n_edges + 8191) / 8192;      // 391
    k_binA<<<blocks_binA, 512, 0, stream>>>(edges, bcursor, pairs, n_edges, nb);

    k_binB<<<nb, 512, 0, stream>>>(bcursor, pairs, offs, counts, n);

    int blocks_waves = ((long)n * 64 + 255) / 256;  // wave per dst
    k_gather<<<blocks_waves, 256, 0, stream>>>(offs, counts, (const int*)pairs, h16,
                                               s_i, s_j, bias, (float*)d_out, n);
}